// Round 1
// baseline (423.423 us; speedup 1.0000x reference)
//
#include <hip/hip_runtime.h>

// TripleBatchTransform: roll(move) -> +noise*0.04 -> pairwise mean-pool
// (written twice) -> per-row standardize.
//
// Math: pooled p[j] = 0.5*(z[2j]+z[2j+1]), z[i] = x[(i-move)%L] + 0.04*noise[i].
// Repeated-twice signal has mean/std identical to mean/std over pooled values,
// so: pass 1 reduces sum/sumsq of pooled; pass 2 recomputes pooled (x re-read
// is L3-resident: whole input = 204.8 MB < 256 MB Infinity Cache) and writes
// (p-mu)*inv_sd to both output slots as one aligned float2 store.

#define THREADS 1024
#define NWAVES (THREADS / 64)

__global__ __launch_bounds__(THREADS) void tbt_kernel(
    const float* __restrict__ x,
    const float* __restrict__ noise,
    const int* __restrict__ movep,
    float* __restrict__ out,
    int L)
{
    const int b   = blockIdx.x;
    const int tid = threadIdx.x;
    const int J   = L >> 1;  // pooled count per row

    int mv = movep[0];
    mv %= L;
    if (mv < 0) mv += L;

    const float* __restrict__ xrow = x + (size_t)b * (size_t)L;
    float* __restrict__ orow       = out + (size_t)b * (size_t)L;

    // mv even && L even => s = (2j - mv) mod L is always even, pair never
    // wraps mid-load, and float2 load is 8B-aligned. Wave-uniform branch.
    const bool fastpair = ((mv & 1) == 0) && ((L & 1) == 0);

    float sum = 0.f, sumsq = 0.f;

    for (int j = tid; j < J; j += THREADS) {
        int s = 2 * j - mv;
        if (s < 0) s += L;
        float a, c;
        if (fastpair) {
            float2 v = *(const float2*)(xrow + s);
            a = v.x; c = v.y;
        } else {
            int s1 = s + 1; if (s1 >= L) s1 -= L;
            a = xrow[s]; c = xrow[s1];
        }
        float2 nv = *(const float2*)(noise + 2 * j);
        float p = 0.5f * (a + c + 0.04f * (nv.x + nv.y));
        sum   += p;
        sumsq += p * p;
    }

    // wave (64-lane) reduction
    #pragma unroll
    for (int off = 32; off > 0; off >>= 1) {
        sum   += __shfl_down(sum,   off, 64);
        sumsq += __shfl_down(sumsq, off, 64);
    }

    __shared__ float s_sum[NWAVES], s_sq[NWAVES];
    __shared__ float s_mu, s_isd;
    const int wave = tid >> 6;
    const int lane = tid & 63;
    if (lane == 0) { s_sum[wave] = sum; s_sq[wave] = sumsq; }
    __syncthreads();
    if (tid == 0) {
        float ts = 0.f, tq = 0.f;
        #pragma unroll
        for (int w = 0; w < NWAVES; ++w) { ts += s_sum[w]; tq += s_sq[w]; }
        float invJ = 1.0f / (float)J;
        float mu   = ts * invJ;
        float var  = tq * invJ - mu * mu;
        s_mu  = mu;
        s_isd = rsqrtf(fmaxf(var, 1e-30f));
    }
    __syncthreads();
    const float mu  = s_mu;
    const float isd = s_isd;

    // pass 2: recompute pooled (x re-read should hit L3), write both slots
    for (int j = tid; j < J; j += THREADS) {
        int s = 2 * j - mv;
        if (s < 0) s += L;
        float a, c;
        if (fastpair) {
            float2 v = *(const float2*)(xrow + s);
            a = v.x; c = v.y;
        } else {
            int s1 = s + 1; if (s1 >= L) s1 -= L;
            a = xrow[s]; c = xrow[s1];
        }
        float2 nv = *(const float2*)(noise + 2 * j);
        float p = 0.5f * (a + c + 0.04f * (nv.x + nv.y));
        float r = (p - mu) * isd;
        *(float2*)(orow + 2 * j) = make_float2(r, r);
    }
}

extern "C" void kernel_launch(void* const* d_in, const int* in_sizes, int n_in,
                              void* d_out, int out_size, void* d_ws, size_t ws_size,
                              hipStream_t stream) {
    const float* x     = (const float*)d_in[0];
    const float* noise = (const float*)d_in[1];
    const int*   move  = (const int*)d_in[2];
    float*       out   = (float*)d_out;

    const int L = in_sizes[1];             // 100000
    const int B = in_sizes[0] / L;         // 512

    tbt_kernel<<<B, THREADS, 0, stream>>>(x, noise, move, out, L);
}